// Round 12
// baseline (141.891 us; speedup 1.0000x reference)
//
#include <hip/hip_runtime.h>

typedef __attribute__((ext_vector_type(4))) float f32x4;

#define NT 256
#define S 10
#define D 100
#define H 16
#define NITER 5
#define LPR 4               // search: lanes per batch row
#define RPB (NT / LPR)      // search: 64 batch rows per block
#define RQ 25               // out-staging row stride in quads (24 used + 1 pad)
#define OUTQ 24             // quads per output row (6*16 floats)
#define WS_NEEDED ((size_t)65536 * S * H * 4)   // 41.9 MB ic buffer

// Wave-uniform weight/bias reads straight from global -> s_load via the
// scalar/constant cache, SGPR operands into v_fma. No LDS weight tile =>
// no VGPR promotion balloon => no spill (r10/r11: WRITE == output exactly).
#define WQ(base, d, q) (*(const f32x4*)&(base)[(d) * H + (q) * 4])

// ============ Kernel A: projection, one thread per (b,s) row ============
// 655360 threads = 10 waves/SIMD offered; VGPR capped at 64 (state ~30)
// -> 8 waves/SIMD resident. Zero divergence, zero LDS, pure stream:
// 400B sequential read + 64B coalesced write per thread.
__global__ __launch_bounds__(NT, 8)
void proj_kernel(const float* __restrict__ item_corpus,
                 const float* __restrict__ W_proj,
                 const float* __restrict__ b_proj,
                 float* __restrict__ ic_ws)
{
    const size_t gid = (size_t)blockIdx.x * NT + threadIdx.x;  // = b*10+s
    const f32x4* crow = (const f32x4*)item_corpus + gid * (D / 4);

    // d-ascending accumulation order (bit-identical to all passing rounds)
    f32x4 a0 = *(const f32x4*)&b_proj[0];
    f32x4 a1 = *(const f32x4*)&b_proj[4];
    f32x4 a2 = *(const f32x4*)&b_proj[8];
    f32x4 a3 = *(const f32x4*)&b_proj[12];
    #pragma unroll 5
    for (int i = 0; i < D / 4; ++i) {
        f32x4 c = crow[i];
        #pragma unroll
        for (int dd = 0; dd < 4; ++dd) {
            float a = c[dd];
            const int d = i * 4 + dd;
            a0 += a * WQ(W_proj, d, 0);
            a1 += a * WQ(W_proj, d, 1);
            a2 += a * WQ(W_proj, d, 2);
            a3 += a * WQ(W_proj, d, 3);
        }
    }
    f32x4* wout = (f32x4*)ic_ws + gid * 4;
    wout[0] = a0; wout[1] = a1; wout[2] = a2; wout[3] = a3;
}

// ============ Kernel B: greedy search (r11's verified phase) ============
__global__ __launch_bounds__(NT, 1)
void search_kernel(const float* __restrict__ user_intent,
                   const float* __restrict__ ic_ws,
                   const float* __restrict__ W_k,
                   const float* __restrict__ b_k,
                   float* __restrict__ out)
{
    __shared__ f32x4 s_out[RPB * RQ];      // 25.6 KB out staging (only LDS)

    const int t = threadIdx.x;
    const int quarter = t & 3;
    const int r = t >> 2;
    const size_t b = (size_t)blockIdx.x * RPB + r;
    const bool has3 = (quarter < 2);
    const int sbase = has3 ? quarter * 3 : 2 + quarter * 2;  // rows {3,3,2,2}

    // bias: uniform -> SGPRs
    f32x4 bk[4];
    #pragma unroll
    for (int q = 0; q < 4; ++q) bk[q] = *(const f32x4*)&b_k[q * 4];

    // this lane's ic rows from ws: contiguous 128-192B
    const f32x4* icin = (const f32x4*)ic_ws + (b * S + sbase) * 4;
    f32x4 ic[3][4];
    #pragma unroll
    for (int ls = 0; ls < 3; ++ls)
        if (ls < 2 || has3)
            #pragma unroll
            for (int q = 0; q < 4; ++q)
                ic[ls][q] = icin[ls * 4 + q];

    const f32x4* urow = (const f32x4*)user_intent + b * 4;
    f32x4 usum[4];
    #pragma unroll
    for (int q = 0; q < 4; ++q) {
        usum[q] = urow[q];
        if (quarter == 0) s_out[r * RQ + q] = usum[q];   // ui[:,0,:]
    }

    #pragma unroll 1
    for (int it = 0; it < NITER; ++it) {
        // ic = ic @ Wk + bk, in place per local row (k ascending)
        #pragma unroll
        for (int ls = 0; ls < 3; ++ls) {
            if (ls < 2 || has3) {
                f32x4 n0 = bk[0], n1 = bk[1], n2 = bk[2], n3 = bk[3];
                #pragma unroll
                for (int k = 0; k < H; ++k) {
                    float a = ic[ls][k >> 2][k & 3];
                    n0 += a * WQ(W_k, k, 0);
                    n1 += a * WQ(W_k, k, 1);
                    n2 += a * WQ(W_k, k, 2);
                    n3 += a * WQ(W_k, k, 3);
                }
                ic[ls][0] = n0; ic[ls][1] = n1; ic[ls][2] = n2; ic[ls][3] = n3;
            }
        }

        float cnt = (float)(it + 1);
        f32x4 src[4];
        #pragma unroll
        for (int q = 0; q < 4; ++q) src[q] = usum[q] / cnt;

        float best = -__builtin_inff();
        int gidx = sbase;
        #pragma unroll
        for (int ls = 0; ls < 3; ++ls) {
            if (ls < 2 || has3) {
                float sc = 0.0f;
                #pragma unroll
                for (int q = 0; q < 4; ++q)
                    #pragma unroll
                    for (int c = 0; c < 4; ++c)
                        sc += ic[ls][q][c] * src[q][c];
                if (sc > best) { best = sc; gidx = sbase + ls; }
            }
        }

        // lexicographic (score, -idx) over the 4-lane group == first-max
        #pragma unroll
        for (int off = 1; off <= 2; off <<= 1) {
            float osc = __shfl_xor(best, off);
            int oidx = __shfl_xor(gidx, off);
            if (osc > best || (osc == best && oidx < gidx)) { best = osc; gidx = oidx; }
        }

        // item_vec broadcast: owner selects, others 0, xor-sum (x+0+0+0 exact)
        f32x4 iv[4];
        #pragma unroll
        for (int q = 0; q < 4; ++q) iv[q] = f32x4{0.f, 0.f, 0.f, 0.f};
        #pragma unroll
        for (int ls = 0; ls < 3; ++ls) {
            if (ls < 2 || has3) {
                bool take = ((sbase + ls) == gidx);
                #pragma unroll
                for (int q = 0; q < 4; ++q)
                    iv[q] = take ? ic[ls][q] : iv[q];
            }
        }
        #pragma unroll
        for (int off = 1; off <= 2; off <<= 1)
            #pragma unroll
            for (int q = 0; q < 4; ++q)
                #pragma unroll
                for (int c = 0; c < 4; ++c)
                    iv[q][c] += __shfl_xor(iv[q][c], off);

        #pragma unroll
        for (int q = 0; q < 4; ++q) {
            usum[q] += iv[q];
            if (quarter == 0) s_out[r * RQ + (it + 1) * 4 + q] = iv[q];
        }
    }

    __syncthreads();
    f32x4* out4 = (f32x4*)out;
    const size_t obase = (size_t)blockIdx.x * RPB * OUTQ;
    #pragma unroll
    for (int k = 0; k < (RPB * OUTQ) / NT; ++k) {
        int j = t + k * NT;
        int row = j / OUTQ;
        int q = j - row * OUTQ;
        out4[obase + j] = s_out[row * RQ + q];
    }
}

// ============ Fallback: round-11 fused kernel (112.9 us) ============
__global__ __launch_bounds__(NT, 1)
void fused_kernel(const float* __restrict__ user_intent,
                  const float* __restrict__ item_corpus,
                  const float* __restrict__ W_proj,
                  const float* __restrict__ b_proj,
                  const float* __restrict__ W_k,
                  const float* __restrict__ b_k,
                  float* __restrict__ out)
{
    __shared__ f32x4 s_out[RPB * RQ];
    const int t = threadIdx.x;
    const int quarter = t & 3;
    const int r = t >> 2;
    const size_t b = (size_t)blockIdx.x * RPB + r;
    const bool has3 = (quarter < 2);
    const int sbase = has3 ? quarter * 3 : 2 + quarter * 2;
    const f32x4* crow = (const f32x4*)item_corpus + b * (S * D / 4) + sbase * (D / 4);
    f32x4 bp[4], bk[4];
    #pragma unroll
    for (int q = 0; q < 4; ++q) {
        bp[q] = *(const f32x4*)&b_proj[q * 4];
        bk[q] = *(const f32x4*)&b_k[q * 4];
    }
    const f32x4* urow = (const f32x4*)user_intent + b * 4;
    f32x4 usum[4];
    #pragma unroll
    for (int q = 0; q < 4; ++q) {
        usum[q] = urow[q];
        if (quarter == 0) s_out[r * RQ + q] = usum[q];
    }
    f32x4 ic[3][4];
    #pragma unroll
    for (int ls = 0; ls < 3; ++ls) {
        if (ls < 2 || has3) {
            f32x4 a0 = bp[0], a1 = bp[1], a2 = bp[2], a3 = bp[3];
            #pragma unroll 5
            for (int i = 0; i < D / 4; ++i) {
                f32x4 c = crow[ls * (D / 4) + i];
                #pragma unroll
                for (int dd = 0; dd < 4; ++dd) {
                    float a = c[dd];
                    const int d = i * 4 + dd;
                    a0 += a * WQ(W_proj, d, 0);
                    a1 += a * WQ(W_proj, d, 1);
                    a2 += a * WQ(W_proj, d, 2);
                    a3 += a * WQ(W_proj, d, 3);
                }
            }
            ic[ls][0] = a0; ic[ls][1] = a1; ic[ls][2] = a2; ic[ls][3] = a3;
        }
    }
    #pragma unroll 1
    for (int it = 0; it < NITER; ++it) {
        #pragma unroll
        for (int ls = 0; ls < 3; ++ls) {
            if (ls < 2 || has3) {
                f32x4 n0 = bk[0], n1 = bk[1], n2 = bk[2], n3 = bk[3];
                #pragma unroll
                for (int k = 0; k < H; ++k) {
                    float a = ic[ls][k >> 2][k & 3];
                    n0 += a * WQ(W_k, k, 0);
                    n1 += a * WQ(W_k, k, 1);
                    n2 += a * WQ(W_k, k, 2);
                    n3 += a * WQ(W_k, k, 3);
                }
                ic[ls][0] = n0; ic[ls][1] = n1; ic[ls][2] = n2; ic[ls][3] = n3;
            }
        }
        float cnt = (float)(it + 1);
        f32x4 src[4];
        #pragma unroll
        for (int q = 0; q < 4; ++q) src[q] = usum[q] / cnt;
        float best = -__builtin_inff();
        int gidx = sbase;
        #pragma unroll
        for (int ls = 0; ls < 3; ++ls) {
            if (ls < 2 || has3) {
                float sc = 0.0f;
                #pragma unroll
                for (int q = 0; q < 4; ++q)
                    #pragma unroll
                    for (int c = 0; c < 4; ++c)
                        sc += ic[ls][q][c] * src[q][c];
                if (sc > best) { best = sc; gidx = sbase + ls; }
            }
        }
        #pragma unroll
        for (int off = 1; off <= 2; off <<= 1) {
            float osc = __shfl_xor(best, off);
            int oidx = __shfl_xor(gidx, off);
            if (osc > best || (osc == best && oidx < gidx)) { best = osc; gidx = oidx; }
        }
        f32x4 iv[4];
        #pragma unroll
        for (int q = 0; q < 4; ++q) iv[q] = f32x4{0.f, 0.f, 0.f, 0.f};
        #pragma unroll
        for (int ls = 0; ls < 3; ++ls) {
            if (ls < 2 || has3) {
                bool take = ((sbase + ls) == gidx);
                #pragma unroll
                for (int q = 0; q < 4; ++q)
                    iv[q] = take ? ic[ls][q] : iv[q];
            }
        }
        #pragma unroll
        for (int off = 1; off <= 2; off <<= 1)
            #pragma unroll
            for (int q = 0; q < 4; ++q)
                #pragma unroll
                for (int c = 0; c < 4; ++c)
                    iv[q][c] += __shfl_xor(iv[q][c], off);
        #pragma unroll
        for (int q = 0; q < 4; ++q) {
            usum[q] += iv[q];
            if (quarter == 0) s_out[r * RQ + (it + 1) * 4 + q] = iv[q];
        }
    }
    __syncthreads();
    f32x4* out4 = (f32x4*)out;
    const size_t obase = (size_t)blockIdx.x * RPB * OUTQ;
    #pragma unroll
    for (int k = 0; k < (RPB * OUTQ) / NT; ++k) {
        int j = t + k * NT;
        int row = j / OUTQ;
        int q = j - row * OUTQ;
        out4[obase + j] = s_out[row * RQ + q];
    }
}

extern "C" void kernel_launch(void* const* d_in, const int* in_sizes, int n_in,
                              void* d_out, int out_size, void* d_ws, size_t ws_size,
                              hipStream_t stream) {
    const float* user_intent = (const float*)d_in[0];
    const float* item_corpus = (const float*)d_in[1];
    const float* W_proj      = (const float*)d_in[2];
    const float* b_proj      = (const float*)d_in[3];
    const float* W_k         = (const float*)d_in[4];
    const float* b_k         = (const float*)d_in[5];
    float* out = (float*)d_out;
    const int bs = 65536;

    if (ws_size >= WS_NEEDED) {
        float* ic_ws = (float*)d_ws;
        hipLaunchKernelGGL(proj_kernel,
                           dim3(bs * S / NT), dim3(NT), 0, stream,
                           item_corpus, W_proj, b_proj, ic_ws);
        hipLaunchKernelGGL(search_kernel,
                           dim3(bs / RPB), dim3(NT), 0, stream,
                           user_intent, ic_ws, W_k, b_k, out);
    } else {
        hipLaunchKernelGGL(fused_kernel,
                           dim3(bs / RPB), dim3(NT), 0, stream,
                           user_intent, item_corpus, W_proj, b_proj, W_k, b_k, out);
    }
}